// Round 1
// baseline (887.323 us; speedup 1.0000x reference)
//
#include <hip/hip_runtime.h>

// Problem constants (from reference): T=2000 frames, B=64 batch, C=256 vocab, L=200 targets.
#define T_FRAMES 2000
#define BATCH    64
#define CVOC     256
#define LTGT     200
#define NEG_INF  (-1e30f)

// ---------------------------------------------------------------------------
// Kernel 1: lse[b*T + t] = logsumexp_c x[t, b, c].
// One wave per (t,b) row: lane loads float4 (contiguous 1 KiB per row),
// shuffle-reduce max then sum(exp).
// ---------------------------------------------------------------------------
__global__ __launch_bounds__(256) void lse_kernel(const float* __restrict__ x,
                                                  float* __restrict__ lse) {
    const int wave = threadIdx.x >> 6;
    const int lane = threadIdx.x & 63;
    const int r = blockIdx.x * 4 + wave;          // r = t*B + b  (rows are contiguous)
    const float4* row = (const float4*)(x + (size_t)r * CVOC);
    float4 v = row[lane];
    float m = fmaxf(fmaxf(v.x, v.y), fmaxf(v.z, v.w));
#pragma unroll
    for (int s = 1; s < 64; s <<= 1) m = fmaxf(m, __shfl_xor(m, s, 64));
    float ssum = __expf(v.x - m) + __expf(v.y - m) + __expf(v.z - m) + __expf(v.w - m);
#pragma unroll
    for (int s = 1; s < 64; s <<= 1) ssum += __shfl_xor(ssum, s, 64);
    if (lane == 0) {
        const int t = r >> 6;      // / BATCH (=64)
        const int b = r & 63;      // % BATCH
        lse[b * T_FRAMES + t] = m + __logf(ssum);   // [b][t] layout -> coalesced reads in dp
    }
}

// logaddexp, safe for the -1e30 "neg-inf" sentinel (stays finite, matches ref).
__device__ __forceinline__ float lae(float a, float b) {
    float m = fmaxf(a, b);
    float d = fminf(a, b) - m;          // <= 0
    return m + __logf(1.0f + __expf(d));
}

// ---------------------------------------------------------------------------
// Kernel 2: forward DP. One wave (64 threads) per batch element.
// Lane k owns l = 4k..4k+3 (L=200 -> lanes 0..49 active, rest compute garbage
// harmlessly). alpha[l-1] across the lane boundary via one shfl_up per step.
// Emission gathers are software-pipelined 2 steps deep.
// ---------------------------------------------------------------------------
__global__ __launch_bounds__(64) void dp_kernel(const float* __restrict__ x,
                                                const int* __restrict__ targets,
                                                const float* __restrict__ lse,
                                                float* __restrict__ part) {
    __shared__ float s_lse[T_FRAMES];   // 8000 B
    const int b = blockIdx.x;
    const int lane = threadIdx.x;

    for (int i = lane; i < T_FRAMES; i += 64) s_lse[i] = lse[b * T_FRAMES + i];

    const int* tg = targets + b * LTGT;
    const int l0 = lane * 4;
    const int i0 = tg[(l0 + 0 < LTGT) ? (l0 + 0) : (LTGT - 1)];
    const int i1 = tg[(l0 + 1 < LTGT) ? (l0 + 1) : (LTGT - 1)];
    const int i2 = tg[(l0 + 2 < LTGT) ? (l0 + 2) : (LTGT - 1)];
    const int i3 = tg[(l0 + 3 < LTGT) ? (l0 + 3) : (LTGT - 1)];

    const float* xb = x + b * CVOC;     // row t lives at xb + t*BATCH*CVOC
    __syncthreads();

    // t = 0: alpha[0] = emit(0,0), rest = NEG_INF
    float a0 = (lane == 0) ? (xb[i0] - s_lse[0]) : NEG_INF;
    float a1 = NEG_INF, a2 = NEG_INF, a3 = NEG_INF;

    // prefetch rows t=1 (A) and t=2 (B)
    const float* rA = xb + (size_t)1 * BATCH * CVOC;
    float pa0 = rA[i0], pa1 = rA[i1], pa2 = rA[i2], pa3 = rA[i3];
    const float* rB = xb + (size_t)2 * BATCH * CVOC;
    float pb0 = rB[i0], pb1 = rB[i1], pb2 = rB[i2], pb3 = rB[i3];

#define DP_STEP(e0, e1, e2, e3, tt)                                   \
    {                                                                 \
        const float ls = s_lse[tt];                                   \
        float prev = __shfl_up(a3, 1, 64);                            \
        if (lane == 0) prev = NEG_INF;                                \
        const float n0 = ((e0) - ls) + lae(a0, prev);                 \
        const float n1 = ((e1) - ls) + lae(a1, a0);                   \
        const float n2 = ((e2) - ls) + lae(a2, a1);                   \
        const float n3 = ((e3) - ls) + lae(a3, a2);                   \
        a0 = n0; a1 = n1; a2 = n2; a3 = n3;                           \
    }

    int t = 1;
    while (t < T_FRAMES) {
        DP_STEP(pa0, pa1, pa2, pa3, t);
        {
            const int tn = (t + 2 < T_FRAMES) ? (t + 2) : (T_FRAMES - 1);
            const float* r = xb + (size_t)tn * BATCH * CVOC;
            pa0 = r[i0]; pa1 = r[i1]; pa2 = r[i2]; pa3 = r[i3];
        }
        ++t;
        if (t >= T_FRAMES) break;
        DP_STEP(pb0, pb1, pb2, pb3, t);
        {
            const int tn = (t + 2 < T_FRAMES) ? (t + 2) : (T_FRAMES - 1);
            const float* r = xb + (size_t)tn * BATCH * CVOC;
            pb0 = r[i0]; pb1 = r[i1]; pb2 = r[i2]; pb3 = r[i3];
        }
        ++t;
    }
#undef DP_STEP

    // l = L-1 = 199 -> lane 49, slot 3
    const float resv = __shfl(a3, 49, 64);
    if (lane == 0) part[b] = -resv;
}

// ---------------------------------------------------------------------------
// Kernel 3: mean over the 64 per-batch negative log-likelihoods.
// ---------------------------------------------------------------------------
__global__ __launch_bounds__(64) void reduce_kernel(const float* __restrict__ part,
                                                    float* __restrict__ out) {
    float v = part[threadIdx.x];
#pragma unroll
    for (int s = 1; s < 64; s <<= 1) v += __shfl_xor(v, s, 64);
    if (threadIdx.x == 0) out[0] = v * (1.0f / BATCH);
}

extern "C" void kernel_launch(void* const* d_in, const int* in_sizes, int n_in,
                              void* d_out, int out_size, void* d_ws, size_t ws_size,
                              hipStream_t stream) {
    const float* x = (const float*)d_in[0];        // [T, B, C] float32
    const int* targets = (const int*)d_in[1];      // [B, L] int32
    float* out = (float*)d_out;                    // scalar

    // workspace: lse [B*T] floats, then part [B] floats  (~512.25 KiB)
    float* lse = (float*)d_ws;
    float* part = lse + (size_t)BATCH * T_FRAMES;

    lse_kernel<<<T_FRAMES * BATCH / 4, 256, 0, stream>>>(x, lse);
    dp_kernel<<<BATCH, 64, 0, stream>>>(x, targets, lse, part);
    reduce_kernel<<<1, 64, 0, stream>>>(part, out);
}

// Round 2
// 603.752 us; speedup vs baseline: 1.4697x; 1.4697x over previous
//
#include <hip/hip_runtime.h>

// T=2000 frames, B=64 batch, C=256 vocab, L=200 targets.
#define T_FRAMES 2000
#define BATCH    64
#define CVOC     256
#define LTGT     200
#define EPAD     200          // emit row stride in floats (800 B, float4-aligned)
#define NEG_INF  (-1e30f)

// logaddexp, finite-safe for the -1e30 sentinel (matches jnp.logaddexp here).
__device__ __forceinline__ float lae(float a, float b) {
    float m = fmaxf(a, b);
    float d = fminf(a, b) - m;          // <= 0
    return m + __logf(1.0f + __expf(d));
}

// ---------------------------------------------------------------------------
// Fast path kernel 1: fused log-softmax-normalizer + target gather.
// One wave per (t,b) row of x: compute lse via shuffle-reduce, stage the row
// in LDS, gather the 200 target entries, write emit[b][t][0..199] contiguous.
// ---------------------------------------------------------------------------
__global__ __launch_bounds__(256) void emit_kernel(const float* __restrict__ x,
                                                   const int* __restrict__ targets,
                                                   float* __restrict__ emit) {
    __shared__ float s[4][CVOC];
    const int w = threadIdx.x >> 6;
    const int lane = threadIdx.x & 63;
    const int r = blockIdx.x * 4 + w;          // r = t*BATCH + b (rows contiguous)
    const int t = r >> 6;                      // / 64
    const int b = r & 63;                      // % 64

    float4 v = ((const float4*)(x + (size_t)r * CVOC))[lane];
    float m = fmaxf(fmaxf(v.x, v.y), fmaxf(v.z, v.w));
#pragma unroll
    for (int sft = 1; sft < 64; sft <<= 1) m = fmaxf(m, __shfl_xor(m, sft, 64));
    float ss = __expf(v.x - m) + __expf(v.y - m) + __expf(v.z - m) + __expf(v.w - m);
#pragma unroll
    for (int sft = 1; sft < 64; sft <<= 1) ss += __shfl_xor(ss, sft, 64);
    const float lseval = m + __logf(ss);

    s[w][lane * 4 + 0] = v.x;
    s[w][lane * 4 + 1] = v.y;
    s[w][lane * 4 + 2] = v.z;
    s[w][lane * 4 + 3] = v.w;
    const int4 tg = ((const int4*)(targets + b * LTGT))[lane < 50 ? lane : 49];
    __syncthreads();

    if (lane < 50) {
        float4 e;
        e.x = s[w][tg.x] - lseval;
        e.y = s[w][tg.y] - lseval;
        e.z = s[w][tg.z] - lseval;
        e.w = s[w][tg.w] - lseval;
        ((float4*)(emit + ((size_t)b * T_FRAMES + t) * EPAD))[lane] = e;
    }
}

// ---------------------------------------------------------------------------
// Fast path kernel 2: forward DP, one wave per batch element.
// Lane k owns l = 4k..4k+3. Per step: ONE contiguous float4 per lane from
// emit, prefetched 16 deep in a statically-indexed register ring.
// ---------------------------------------------------------------------------
__global__ __launch_bounds__(64) void dp_fast_kernel(const float* __restrict__ emit,
                                                     float* __restrict__ part) {
    const int b = blockIdx.x;
    const int lane = threadIdx.x;
    const float* base = emit + (size_t)b * T_FRAMES * EPAD;
    const int fi = (lane < 50) ? lane : 49;    // float4 index within a row

    // t = 0 init: alpha[0] = emit[b][0][0]
    const float e00 = base[0];
    float a0 = (lane == 0) ? e00 : NEG_INF;
    float a1 = NEG_INF, a2 = NEG_INF, a3 = NEG_INF;

    float4 buf[16];
#pragma unroll
    for (int j = 0; j < 16; ++j)
        buf[j] = ((const float4*)(base + (size_t)(1 + j) * EPAD))[fi];

    float res = 0.0f;
    for (int tb = 1; tb < T_FRAMES; tb += 16) {
#pragma unroll
        for (int j = 0; j < 16; ++j) {
            const int t = tb + j;
            const float4 e = buf[j];
            int tn = t + 16;
            tn = (tn < T_FRAMES) ? tn : (T_FRAMES - 1);       // clamped harmless prefetch
            buf[j] = ((const float4*)(base + (size_t)tn * EPAD))[fi];

            float prev = __shfl_up(a3, 1, 64);
            if (lane == 0) prev = NEG_INF;
            const float n0 = e.x + lae(a0, prev);
            const float n1 = e.y + lae(a1, a0);
            const float n2 = e.z + lae(a2, a1);
            const float n3 = e.w + lae(a3, a2);
            a0 = n0; a1 = n1; a2 = n2; a3 = n3;
            res = (t == T_FRAMES - 1) ? a3 : res;   // capture before the 1 overrun step
        }
    }

    const float resv = __shfl(res, 49, 64);    // l = 199 -> lane 49 slot 3
    if (lane == 0) part[b] = -resv;
}

// ---------------------------------------------------------------------------
// Mean over the 64 per-batch NLLs.
// ---------------------------------------------------------------------------
__global__ __launch_bounds__(64) void reduce_kernel(const float* __restrict__ part,
                                                    float* __restrict__ out) {
    float v = part[threadIdx.x];
#pragma unroll
    for (int s = 1; s < 64; s <<= 1) v += __shfl_xor(v, s, 64);
    if (threadIdx.x == 0) out[0] = v * (1.0f / BATCH);
}

// ===========================================================================
// Fallback path (round-1, verified correct at 887 us) if ws_size < ~103 MB.
// ===========================================================================
__global__ __launch_bounds__(256) void lse_kernel(const float* __restrict__ x,
                                                  float* __restrict__ lse) {
    const int wave = threadIdx.x >> 6;
    const int lane = threadIdx.x & 63;
    const int r = blockIdx.x * 4 + wave;
    const float4* row = (const float4*)(x + (size_t)r * CVOC);
    float4 v = row[lane];
    float m = fmaxf(fmaxf(v.x, v.y), fmaxf(v.z, v.w));
#pragma unroll
    for (int s = 1; s < 64; s <<= 1) m = fmaxf(m, __shfl_xor(m, s, 64));
    float ssum = __expf(v.x - m) + __expf(v.y - m) + __expf(v.z - m) + __expf(v.w - m);
#pragma unroll
    for (int s = 1; s < 64; s <<= 1) ssum += __shfl_xor(ssum, s, 64);
    if (lane == 0) {
        const int t = r >> 6;
        const int b = r & 63;
        lse[b * T_FRAMES + t] = m + __logf(ssum);
    }
}

__global__ __launch_bounds__(64) void dp_slow_kernel(const float* __restrict__ x,
                                                     const int* __restrict__ targets,
                                                     const float* __restrict__ lse,
                                                     float* __restrict__ part) {
    __shared__ float s_lse[T_FRAMES];
    const int b = blockIdx.x;
    const int lane = threadIdx.x;
    for (int i = lane; i < T_FRAMES; i += 64) s_lse[i] = lse[b * T_FRAMES + i];
    const int* tg = targets + b * LTGT;
    const int l0 = lane * 4;
    const int i0 = tg[(l0 + 0 < LTGT) ? (l0 + 0) : (LTGT - 1)];
    const int i1 = tg[(l0 + 1 < LTGT) ? (l0 + 1) : (LTGT - 1)];
    const int i2 = tg[(l0 + 2 < LTGT) ? (l0 + 2) : (LTGT - 1)];
    const int i3 = tg[(l0 + 3 < LTGT) ? (l0 + 3) : (LTGT - 1)];
    const float* xb = x + b * CVOC;
    __syncthreads();
    float a0 = (lane == 0) ? (xb[i0] - s_lse[0]) : NEG_INF;
    float a1 = NEG_INF, a2 = NEG_INF, a3 = NEG_INF;
    const float* rA = xb + (size_t)1 * BATCH * CVOC;
    float pa0 = rA[i0], pa1 = rA[i1], pa2 = rA[i2], pa3 = rA[i3];
    const float* rB = xb + (size_t)2 * BATCH * CVOC;
    float pb0 = rB[i0], pb1 = rB[i1], pb2 = rB[i2], pb3 = rB[i3];
#define DP_STEP(e0, e1, e2, e3, tt)                                   \
    {                                                                 \
        const float ls = s_lse[tt];                                   \
        float prev = __shfl_up(a3, 1, 64);                            \
        if (lane == 0) prev = NEG_INF;                                \
        const float n0 = ((e0) - ls) + lae(a0, prev);                 \
        const float n1 = ((e1) - ls) + lae(a1, a0);                   \
        const float n2 = ((e2) - ls) + lae(a2, a1);                   \
        const float n3 = ((e3) - ls) + lae(a3, a2);                   \
        a0 = n0; a1 = n1; a2 = n2; a3 = n3;                           \
    }
    int t = 1;
    while (t < T_FRAMES) {
        DP_STEP(pa0, pa1, pa2, pa3, t);
        {
            const int tn = (t + 2 < T_FRAMES) ? (t + 2) : (T_FRAMES - 1);
            const float* r = xb + (size_t)tn * BATCH * CVOC;
            pa0 = r[i0]; pa1 = r[i1]; pa2 = r[i2]; pa3 = r[i3];
        }
        ++t;
        if (t >= T_FRAMES) break;
        DP_STEP(pb0, pb1, pb2, pb3, t);
        {
            const int tn = (t + 2 < T_FRAMES) ? (t + 2) : (T_FRAMES - 1);
            const float* r = xb + (size_t)tn * BATCH * CVOC;
            pb0 = r[i0]; pb1 = r[i1]; pb2 = r[i2]; pb3 = r[i3];
        }
        ++t;
    }
#undef DP_STEP
    const float resv = __shfl(a3, 49, 64);
    if (lane == 0) part[b] = -resv;
}

extern "C" void kernel_launch(void* const* d_in, const int* in_sizes, int n_in,
                              void* d_out, int out_size, void* d_ws, size_t ws_size,
                              hipStream_t stream) {
    const float* x = (const float*)d_in[0];        // [T, B, C] float32
    const int* targets = (const int*)d_in[1];      // [B, L] int32
    float* out = (float*)d_out;

    const size_t emit_bytes = (size_t)BATCH * T_FRAMES * EPAD * sizeof(float); // 102.4 MB
    if (ws_size >= emit_bytes + 4096) {
        float* emit = (float*)d_ws;
        float* part = (float*)((char*)d_ws + emit_bytes);
        emit_kernel<<<T_FRAMES * BATCH / 4, 256, 0, stream>>>(x, targets, emit);
        dp_fast_kernel<<<BATCH, 64, 0, stream>>>(emit, part);
        reduce_kernel<<<1, 64, 0, stream>>>(part, out);
    } else {
        float* lse = (float*)d_ws;
        float* part = lse + (size_t)BATCH * T_FRAMES;
        lse_kernel<<<T_FRAMES * BATCH / 4, 256, 0, stream>>>(x, lse);
        dp_slow_kernel<<<BATCH, 64, 0, stream>>>(x, targets, lse, part);
        reduce_kernel<<<1, 64, 0, stream>>>(part, out);
    }
}

// Round 4
// 601.030 us; speedup vs baseline: 1.4763x; 1.0045x over previous
//
#include <hip/hip_runtime.h>

// T=2000 frames, B=64 batch, C=256 vocab, L=200 targets.
#define T_FRAMES 2000
#define BATCH    64
#define CVOC     256
#define LTGT     200
#define EPAD     200                  // emit row stride in floats (800 B, dense)
#define CHUNK    32                   // emit rows per LDS chunk (25600 B = 25 x 1024 B DMA)
#define NCHUNK   63                   // ceil(2000/32)
#define NEG_INF  (-1e30f)
#define INV_LN2  1.4426950408889634f
#define LN2      0.6931471805599453f

// Raw v_exp_f32 (2^x) / v_log_f32 (log2 x). __exp2f/__log2f collide with
// glibc math.h reserved names in the -x hip TU — use the amdgcn builtins.
#if __has_builtin(__builtin_amdgcn_exp2f)
__device__ __forceinline__ float fexp2(float x) { return __builtin_amdgcn_exp2f(x); }
#else
__device__ __forceinline__ float fexp2(float x) { return exp2f(x); }
#endif
#if __has_builtin(__builtin_amdgcn_logf)
__device__ __forceinline__ float flog2(float x) { return __builtin_amdgcn_logf(x); }
#else
__device__ __forceinline__ float flog2(float x) { return log2f(x); }
#endif

// ---------------------------------------------------------------------------
// DPP helpers (VALU cross-lane, no LDS round-trip).
// ---------------------------------------------------------------------------
// wave_shr:1 — lane i gets lane i-1's v; lane 0 gets `fill`.
__device__ __forceinline__ float dpp_shr1_wave(float v, float fill) {
    return __int_as_float(__builtin_amdgcn_update_dpp(
        __float_as_int(fill), __float_as_int(v), 0x138, 0xF, 0xF, false));
}
// generic DPP term, 0-fill for invalid lanes (identity for sum; for max it
// only ever injects 0, which is a consistent — hence exact — stabilizer).
template <int CTRL, int RMASK>
__device__ __forceinline__ float dpp_term(float v) {
    return __int_as_float(__builtin_amdgcn_update_dpp(
        0, __float_as_int(v), CTRL, RMASK, 0xF, true));
}
__device__ __forceinline__ float wave_max(float v) {
    v = fmaxf(v, dpp_term<0x111, 0xF>(v));   // row_shr:1
    v = fmaxf(v, dpp_term<0x112, 0xF>(v));   // row_shr:2
    v = fmaxf(v, dpp_term<0x114, 0xF>(v));   // row_shr:4
    v = fmaxf(v, dpp_term<0x118, 0xF>(v));   // row_shr:8
    v = fmaxf(v, dpp_term<0x142, 0xA>(v));   // row_bcast:15 -> rows 1,3
    v = fmaxf(v, dpp_term<0x143, 0xC>(v));   // row_bcast:31 -> rows 2,3
    return __int_as_float(__builtin_amdgcn_readlane(__float_as_int(v), 63));
}
__device__ __forceinline__ float wave_sum(float v) {
    v += dpp_term<0x111, 0xF>(v);
    v += dpp_term<0x112, 0xF>(v);
    v += dpp_term<0x114, 0xF>(v);
    v += dpp_term<0x118, 0xF>(v);
    v += dpp_term<0x142, 0xA>(v);
    v += dpp_term<0x143, 0xC>(v);
    return __int_as_float(__builtin_amdgcn_readlane(__float_as_int(v), 63));
}

// log2-domain logaddexp: lae2(a,b) = log2(2^a + 2^b); finite-safe for -1e30.
__device__ __forceinline__ float lae2(float a, float b) {
    float m = fmaxf(a, b);
    float d = fminf(a, b) - m;          // <= 0
    return m + flog2(1.0f + fexp2(d));
}

// ---------------------------------------------------------------------------
// Kernel 1: fused log-softmax-normalizer + target gather, log2 domain.
// One wave per (t,b) row; DPP reductions (no ds shuffles, no barrier).
// emit[b][t][l] = (x[t,b,tgt[b,l]] - lse) / ln2, rows dense (800 B).
// ---------------------------------------------------------------------------
__global__ __launch_bounds__(256) void emit_kernel(const float* __restrict__ x,
                                                   const int* __restrict__ targets,
                                                   float* __restrict__ emit) {
    __shared__ float s[4][CVOC];
    const int w = threadIdx.x >> 6;
    const int lane = threadIdx.x & 63;
    const int r = blockIdx.x * 4 + w;          // r = t*BATCH + b
    const int t = r >> 6;
    const int b = r & 63;

    float4 v = ((const float4*)(x + (size_t)r * CVOC))[lane];
    v.x *= INV_LN2; v.y *= INV_LN2; v.z *= INV_LN2; v.w *= INV_LN2;
    float m = fmaxf(fmaxf(v.x, v.y), fmaxf(v.z, v.w));
    m = wave_max(m);
    float ss = fexp2(v.x - m) + fexp2(v.y - m) + fexp2(v.z - m) + fexp2(v.w - m);
    ss = wave_sum(ss);
    const float lse2 = m + flog2(ss);

    ((float4*)&s[w][lane * 4])[0] = v;          // stage scaled row (same-wave order)
    const int4 tg = ((const int4*)(targets + b * LTGT))[lane < 50 ? lane : 49];

    if (lane < 50) {
        float4 e;
        e.x = s[w][tg.x] - lse2;
        e.y = s[w][tg.y] - lse2;
        e.z = s[w][tg.z] - lse2;
        e.w = s[w][tg.w] - lse2;
        ((float4*)(emit + ((size_t)b * T_FRAMES + t) * EPAD))[lane] = e;
    }
}

// ---------------------------------------------------------------------------
// Kernel 2: forward DP, one wave per batch. LDS double-buffered DMA staging
// (global_load_lds w16), depth-4 register ring from LDS, DPP shfl, log2 math.
// ---------------------------------------------------------------------------
__device__ __forceinline__ void dma_chunk(const float* src, float* dst, int lane) {
#pragma unroll
    for (int i = 0; i < 25; ++i)
        __builtin_amdgcn_global_load_lds(
            (const __attribute__((address_space(1))) void*)(src + i * 256 + lane * 4),
            (__attribute__((address_space(3))) void*)(dst + i * 256),
            16, 0, 0);
}

__global__ __launch_bounds__(64) void dp_kernel(const float* __restrict__ emit,
                                                float* __restrict__ part) {
    __shared__ float sbuf[2][CHUNK * EPAD];     // 2 x 25600 B
    const int b = blockIdx.x;
    const int lane = threadIdx.x;
    const float* base = emit + (size_t)b * T_FRAMES * EPAD;
    const int fi = (lane < 50) ? lane : 49;

    dma_chunk(base, sbuf[0], lane);                      // chunk 0 (rows 0..31)
    dma_chunk(base + CHUNK * EPAD, sbuf[1], lane);       // chunk 1
    const float e00 = base[0];

    __builtin_amdgcn_s_waitcnt(0x0F70);                  // vmcnt(0): chunks 0,1 ready

    float a0 = (lane == 0) ? e00 : NEG_INF;
    float a1 = NEG_INF, a2 = NEG_INF, a3 = NEG_INF;

    float4 ering[4];                                     // ering[t&3] holds row t
#pragma unroll
    for (int j = 1; j <= 4; ++j)
        ering[j & 3] = ((const float4*)(sbuf[0] + j * EPAD))[fi];

#pragma unroll 4
    for (int t = 1; t < T_FRAMES; ++t) {
        if ((t & 31) == 0) {                             // entering chunk t>>5
            const int cn = (t >> 5) + 1;
            if (cn < NCHUNK)
                dma_chunk(base + (size_t)cn * CHUNK * EPAD, sbuf[cn & 1], lane);
        }
        if ((t & 31) == 27)                              // next chunk's DMA done
            __builtin_amdgcn_s_waitcnt(0x0F70);          // before cross-buffer prefetch

        const float4 e = ering[t & 3];
        {                                                // prefetch row t+4
            const int tp = t + 4;
            const float* bufp = sbuf[(tp >> 5) & 1];
            ering[t & 3] = ((const float4*)(bufp + (tp & 31) * EPAD))[fi];
        }
        const float prev = dpp_shr1_wave(a3, NEG_INF);
        const float n0 = e.x + lae2(a0, prev);
        const float n1 = e.y + lae2(a1, a0);
        const float n2 = e.z + lae2(a2, a1);
        const float n3 = e.w + lae2(a3, a2);
        a0 = n0; a1 = n1; a2 = n2; a3 = n3;
    }

    const float res = __int_as_float(__builtin_amdgcn_readlane(__float_as_int(a3), 49));
    if (lane == 0) part[b] = -res * LN2;                 // back to natural log
}

// ---------------------------------------------------------------------------
// Kernel 3: mean over the 64 per-batch NLLs.
// ---------------------------------------------------------------------------
__global__ __launch_bounds__(64) void reduce_kernel(const float* __restrict__ part,
                                                    float* __restrict__ out) {
    float v = part[threadIdx.x];
#pragma unroll
    for (int s = 1; s < 64; s <<= 1) v += __shfl_xor(v, s, 64);
    if (threadIdx.x == 0) out[0] = v * (1.0f / BATCH);
}

// ===========================================================================
// Fallback path (round-1, natural-log domain) if ws too small.
// ===========================================================================
__device__ __forceinline__ float lae(float a, float b) {
    float m = fmaxf(a, b);
    float d = fminf(a, b) - m;
    return m + __logf(1.0f + __expf(d));
}

__global__ __launch_bounds__(256) void lse_kernel(const float* __restrict__ x,
                                                  float* __restrict__ lse) {
    const int wave = threadIdx.x >> 6;
    const int lane = threadIdx.x & 63;
    const int r = blockIdx.x * 4 + wave;
    float4 v = ((const float4*)(x + (size_t)r * CVOC))[lane];
    float m = fmaxf(fmaxf(v.x, v.y), fmaxf(v.z, v.w));
#pragma unroll
    for (int s = 1; s < 64; s <<= 1) m = fmaxf(m, __shfl_xor(m, s, 64));
    float ssum = __expf(v.x - m) + __expf(v.y - m) + __expf(v.z - m) + __expf(v.w - m);
#pragma unroll
    for (int s = 1; s < 64; s <<= 1) ssum += __shfl_xor(ssum, s, 64);
    if (lane == 0) {
        const int t = r >> 6;
        const int b = r & 63;
        lse[b * T_FRAMES + t] = m + __logf(ssum);
    }
}

__global__ __launch_bounds__(64) void dp_slow_kernel(const float* __restrict__ x,
                                                     const int* __restrict__ targets,
                                                     const float* __restrict__ lse,
                                                     float* __restrict__ part) {
    __shared__ float s_lse[T_FRAMES];
    const int b = blockIdx.x;
    const int lane = threadIdx.x;
    for (int i = lane; i < T_FRAMES; i += 64) s_lse[i] = lse[b * T_FRAMES + i];
    const int* tg = targets + b * LTGT;
    const int l0 = lane * 4;
    const int i0 = tg[(l0 + 0 < LTGT) ? (l0 + 0) : (LTGT - 1)];
    const int i1 = tg[(l0 + 1 < LTGT) ? (l0 + 1) : (LTGT - 1)];
    const int i2 = tg[(l0 + 2 < LTGT) ? (l0 + 2) : (LTGT - 1)];
    const int i3 = tg[(l0 + 3 < LTGT) ? (l0 + 3) : (LTGT - 1)];
    const float* xb = x + b * CVOC;
    __syncthreads();
    float a0 = (lane == 0) ? (xb[i0] - s_lse[0]) : NEG_INF;
    float a1 = NEG_INF, a2 = NEG_INF, a3 = NEG_INF;
    const float* rA = xb + (size_t)1 * BATCH * CVOC;
    float pa0 = rA[i0], pa1 = rA[i1], pa2 = rA[i2], pa3 = rA[i3];
    const float* rB = xb + (size_t)2 * BATCH * CVOC;
    float pb0 = rB[i0], pb1 = rB[i1], pb2 = rB[i2], pb3 = rB[i3];
#define DP_STEP(e0, e1, e2, e3, tt)                                   \
    {                                                                 \
        const float ls = s_lse[tt];                                   \
        float prev = __shfl_up(a3, 1, 64);                            \
        if (lane == 0) prev = NEG_INF;                                \
        const float n0 = ((e0) - ls) + lae(a0, prev);                 \
        const float n1 = ((e1) - ls) + lae(a1, a0);                   \
        const float n2 = ((e2) - ls) + lae(a2, a1);                   \
        const float n3 = ((e3) - ls) + lae(a3, a2);                   \
        a0 = n0; a1 = n1; a2 = n2; a3 = n3;                           \
    }
    int t = 1;
    while (t < T_FRAMES) {
        DP_STEP(pa0, pa1, pa2, pa3, t);
        {
            const int tn = (t + 2 < T_FRAMES) ? (t + 2) : (T_FRAMES - 1);
            const float* r = xb + (size_t)tn * BATCH * CVOC;
            pa0 = r[i0]; pa1 = r[i1]; pa2 = r[i2]; pa3 = r[i3];
        }
        ++t;
        if (t >= T_FRAMES) break;
        DP_STEP(pb0, pb1, pb2, pb3, t);
        {
            const int tn = (t + 2 < T_FRAMES) ? (t + 2) : (T_FRAMES - 1);
            const float* r = xb + (size_t)tn * BATCH * CVOC;
            pb0 = r[i0]; pb1 = r[i1]; pb2 = r[i2]; pb3 = r[i3];
        }
        ++t;
    }
#undef DP_STEP
    const float resv = __shfl(a3, 49, 64);
    if (lane == 0) part[b] = -resv;
}

extern "C" void kernel_launch(void* const* d_in, const int* in_sizes, int n_in,
                              void* d_out, int out_size, void* d_ws, size_t ws_size,
                              hipStream_t stream) {
    const float* x = (const float*)d_in[0];        // [T, B, C] float32
    const int* targets = (const int*)d_in[1];      // [B, L] int32
    float* out = (float*)d_out;

    const size_t emit_bytes = (size_t)BATCH * T_FRAMES * EPAD * sizeof(float); // 102.4 MB
    // fast path needs slack past emit for the last chunk's DMA over-read
    if (ws_size >= emit_bytes + 32768) {
        float* emit = (float*)d_ws;
        float* part = (float*)((char*)d_ws + emit_bytes + 16384);
        emit_kernel<<<T_FRAMES * BATCH / 4, 256, 0, stream>>>(x, targets, emit);
        dp_kernel<<<BATCH, 64, 0, stream>>>(emit, part);
        reduce_kernel<<<1, 64, 0, stream>>>(part, out);
    } else {
        float* lse = (float*)d_ws;
        float* part = lse + (size_t)BATCH * T_FRAMES;
        lse_kernel<<<T_FRAMES * BATCH / 4, 256, 0, stream>>>(x, lse);
        dp_slow_kernel<<<BATCH, 64, 0, stream>>>(x, targets, lse, part);
        reduce_kernel<<<1, 64, 0, stream>>>(part, out);
    }
}

// Round 5
// 381.125 us; speedup vs baseline: 2.3282x; 1.5770x over previous
//
#include <hip/hip_runtime.h>

// T=2000 frames, B=64 batch, C=256 vocab, L=200 targets.
#define T_FRAMES 2000
#define BATCH    64
#define CVOC     256
#define LTGT     200
#define EPAD     200                  // emit row stride in floats (800 B, dense)
#define SEG      20                   // dp: rows per register segment (20 float4 = 80 VGPR)
#define NSEG     100                  // SEG*NSEG = 2000 steps (t=1..2000; t=2000 discarded)
#define NEG_INF  (-1e30f)
#define INV_LN2  1.4426950408889634f
#define LN2      0.6931471805599453f

// Raw v_exp_f32 (2^x) / v_log_f32 (log2 x). __exp2f/__log2f collide with glibc
// reserved names in the -x hip TU — use the amdgcn builtins.
#if __has_builtin(__builtin_amdgcn_exp2f)
__device__ __forceinline__ float fexp2(float x) { return __builtin_amdgcn_exp2f(x); }
#else
__device__ __forceinline__ float fexp2(float x) { return exp2f(x); }
#endif
#if __has_builtin(__builtin_amdgcn_logf)
__device__ __forceinline__ float flog2(float x) { return __builtin_amdgcn_logf(x); }
#else
__device__ __forceinline__ float flog2(float x) { return log2f(x); }
#endif

// ---------------------------------------------------------------------------
// DPP helpers (VALU cross-lane, no LDS round-trip).
// ---------------------------------------------------------------------------
// wave_shr:1 — lane i gets lane i-1's v; lane 0 gets `fill`.
__device__ __forceinline__ float dpp_shr1_wave(float v, float fill) {
    return __int_as_float(__builtin_amdgcn_update_dpp(
        __float_as_int(fill), __float_as_int(v), 0x138, 0xF, 0xF, false));
}
// generic DPP term, 0-fill for invalid lanes (identity for sum; for max the
// injected 0 only acts as a consistent — hence exact — stabilizer).
template <int CTRL, int RMASK>
__device__ __forceinline__ float dpp_term(float v) {
    return __int_as_float(__builtin_amdgcn_update_dpp(
        0, __float_as_int(v), CTRL, RMASK, 0xF, true));
}
__device__ __forceinline__ float wave_max(float v) {
    v = fmaxf(v, dpp_term<0x111, 0xF>(v));   // row_shr:1
    v = fmaxf(v, dpp_term<0x112, 0xF>(v));   // row_shr:2
    v = fmaxf(v, dpp_term<0x114, 0xF>(v));   // row_shr:4
    v = fmaxf(v, dpp_term<0x118, 0xF>(v));   // row_shr:8
    v = fmaxf(v, dpp_term<0x142, 0xA>(v));   // row_bcast:15 -> rows 1,3
    v = fmaxf(v, dpp_term<0x143, 0xC>(v));   // row_bcast:31 -> rows 2,3
    return __int_as_float(__builtin_amdgcn_readlane(__float_as_int(v), 63));
}
__device__ __forceinline__ float wave_sum(float v) {
    v += dpp_term<0x111, 0xF>(v);
    v += dpp_term<0x112, 0xF>(v);
    v += dpp_term<0x114, 0xF>(v);
    v += dpp_term<0x118, 0xF>(v);
    v += dpp_term<0x142, 0xA>(v);
    v += dpp_term<0x143, 0xC>(v);
    return __int_as_float(__builtin_amdgcn_readlane(__float_as_int(v), 63));
}

// log2-domain logaddexp: lae2(a,b) = log2(2^a + 2^b); finite-safe for -1e30.
__device__ __forceinline__ float lae2(float a, float b) {
    float m = fmaxf(a, b);
    float d = fminf(a, b) - m;          // <= 0
    return m + flog2(1.0f + fexp2(d));
}

// ---------------------------------------------------------------------------
// Kernel 1: fused log-softmax-normalizer + target gather, log2 domain.
// Each wave handles FOUR (t,b) rows: 4 independent float4 loads outstanding
// (latency hiding) + 4 interleaved DPP-reduction pipelines.
// emit[b][t][l] = (x[t,b,tgt[b,l]] - lse) / ln2, rows dense (800 B).
// ---------------------------------------------------------------------------
__global__ __launch_bounds__(256) void emit_kernel(const float* __restrict__ x,
                                                   const int* __restrict__ targets,
                                                   float* __restrict__ emit) {
    __shared__ float s[16][CVOC];                // 16 KB
    const int w = threadIdx.x >> 6;
    const int lane = threadIdx.x & 63;
    const int r0 = blockIdx.x * 16 + w * 4;      // this wave's 4 rows (r = t*64+b)
    const int li = (lane < 50) ? lane : 49;

    float4 v[4];
#pragma unroll
    for (int k = 0; k < 4; ++k)                  // 4 loads, all outstanding
        v[k] = ((const float4*)(x + (size_t)(r0 + k) * CVOC))[lane];
    int4 tg[4];
#pragma unroll
    for (int k = 0; k < 4; ++k)
        tg[k] = ((const int4*)(targets + ((r0 + k) & 63) * LTGT))[li];

    float lse2[4];
#pragma unroll
    for (int k = 0; k < 4; ++k) {
        v[k].x *= INV_LN2; v[k].y *= INV_LN2; v[k].z *= INV_LN2; v[k].w *= INV_LN2;
        float m = fmaxf(fmaxf(v[k].x, v[k].y), fmaxf(v[k].z, v[k].w));
        m = wave_max(m);
        float ss = fexp2(v[k].x - m) + fexp2(v[k].y - m) +
                   fexp2(v[k].z - m) + fexp2(v[k].w - m);
        ss = wave_sum(ss);
        lse2[k] = m + flog2(ss);
        ((float4*)&s[w * 4 + k][lane * 4])[0] = v[k];   // same-wave staging
    }

#pragma unroll
    for (int k = 0; k < 4; ++k) {
        if (lane < 50) {
            const int r = r0 + k;
            const int t = r >> 6;
            const int b = r & 63;
            float4 e;
            e.x = s[w * 4 + k][tg[k].x] - lse2[k];
            e.y = s[w * 4 + k][tg[k].y] - lse2[k];
            e.z = s[w * 4 + k][tg[k].z] - lse2[k];
            e.w = s[w * 4 + k][tg[k].w] - lse2[k];
            ((float4*)(emit + ((size_t)b * T_FRAMES + t) * EPAD))[lane] = e;
        }
    }
}

// ---------------------------------------------------------------------------
// Kernel 2: forward DP, one wave per batch. NO memory ops in the step loop:
// emissions live in two 20-row float4 register buffers, ping-ponged. Loads
// for the next segment issue before computing the current one.
// ---------------------------------------------------------------------------
__device__ __forceinline__ float4 ld_row(const float* base, int t, int fi) {
    return ((const float4*)(base + (size_t)t * EPAD))[fi];
}

__global__ __launch_bounds__(64, 1) void dp_kernel(const float* __restrict__ emit,
                                                   float* __restrict__ part) {
    const int b = blockIdx.x;
    const int lane = threadIdx.x;
    const float* base = emit + (size_t)b * T_FRAMES * EPAD;
    const int fi = (lane < 50) ? lane : 49;

    const float e00 = base[0];
    float a0 = (lane == 0) ? e00 : NEG_INF;
    float a1 = NEG_INF, a2 = NEG_INF, a3 = NEG_INF;
    float res = 0.0f;

    float4 ebA[SEG], ebB[SEG];

#pragma unroll
    for (int j = 0; j < SEG; ++j)                 // segment 0 -> A
        ebA[j] = ld_row(base, 1 + j, fi);

#define DP_STEP(e, tcur)                                              \
    {                                                                 \
        const float prev = dpp_shr1_wave(a3, NEG_INF);                \
        const float n0 = (e).x + lae2(a0, prev);                      \
        const float n1 = (e).y + lae2(a1, a0);                        \
        const float n2 = (e).z + lae2(a2, a1);                        \
        const float n3 = (e).w + lae2(a3, a2);                        \
        a0 = n0; a1 = n1; a2 = n2; a3 = n3;                           \
        res = ((tcur) == T_FRAMES - 1) ? a3 : res;                    \
    }

    // NOTE: segment s covers t = 1+s*SEG .. 1+s*SEG+SEG-1; s=99,j=19 gives
    // t=2000 — an 800 B over-read past this batch's rows (covered by ws slack
    // for b=63), computed then discarded (res captured at t==1999).
    for (int sp = 0; sp < NSEG; sp += 2) {
#pragma unroll
        for (int j = 0; j < SEG; ++j)             // segment sp+1 -> B
            ebB[j] = ld_row(base, 1 + (sp + 1) * SEG + j, fi);
#pragma unroll
        for (int j = 0; j < SEG; ++j)             // compute segment sp (A)
            DP_STEP(ebA[j], 1 + sp * SEG + j);
        if (sp + 2 < NSEG) {
#pragma unroll
            for (int j = 0; j < SEG; ++j)         // segment sp+2 -> A
                ebA[j] = ld_row(base, 1 + (sp + 2) * SEG + j, fi);
        }
#pragma unroll
        for (int j = 0; j < SEG; ++j)             // compute segment sp+1 (B)
            DP_STEP(ebB[j], 1 + (sp + 1) * SEG + j);
    }
#undef DP_STEP

    const float r49 = __int_as_float(__builtin_amdgcn_readlane(__float_as_int(res), 49));
    if (lane == 0) part[b] = -r49 * LN2;          // back to natural log
}

// ---------------------------------------------------------------------------
// Kernel 3: mean over the 64 per-batch NLLs.
// ---------------------------------------------------------------------------
__global__ __launch_bounds__(64) void reduce_kernel(const float* __restrict__ part,
                                                    float* __restrict__ out) {
    float v = part[threadIdx.x];
#pragma unroll
    for (int s = 1; s < 64; s <<= 1) v += __shfl_xor(v, s, 64);
    if (threadIdx.x == 0) out[0] = v * (1.0f / BATCH);
}

// ===========================================================================
// Fallback path (round-1, natural-log domain) if ws too small.
// ===========================================================================
__device__ __forceinline__ float lae(float a, float b) {
    float m = fmaxf(a, b);
    float d = fminf(a, b) - m;
    return m + __logf(1.0f + __expf(d));
}

__global__ __launch_bounds__(256) void lse_kernel(const float* __restrict__ x,
                                                  float* __restrict__ lse) {
    const int wave = threadIdx.x >> 6;
    const int lane = threadIdx.x & 63;
    const int r = blockIdx.x * 4 + wave;
    float4 v = ((const float4*)(x + (size_t)r * CVOC))[lane];
    float m = fmaxf(fmaxf(v.x, v.y), fmaxf(v.z, v.w));
#pragma unroll
    for (int s = 1; s < 64; s <<= 1) m = fmaxf(m, __shfl_xor(m, s, 64));
    float ssum = __expf(v.x - m) + __expf(v.y - m) + __expf(v.z - m) + __expf(v.w - m);
#pragma unroll
    for (int s = 1; s < 64; s <<= 1) ssum += __shfl_xor(ssum, s, 64);
    if (lane == 0) {
        const int t = r >> 6;
        const int b = r & 63;
        lse[b * T_FRAMES + t] = m + __logf(ssum);
    }
}

__global__ __launch_bounds__(64) void dp_slow_kernel(const float* __restrict__ x,
                                                     const int* __restrict__ targets,
                                                     const float* __restrict__ lse,
                                                     float* __restrict__ part) {
    __shared__ float s_lse[T_FRAMES];
    const int b = blockIdx.x;
    const int lane = threadIdx.x;
    for (int i = lane; i < T_FRAMES; i += 64) s_lse[i] = lse[b * T_FRAMES + i];
    const int* tg = targets + b * LTGT;
    const int l0 = lane * 4;
    const int i0 = tg[(l0 + 0 < LTGT) ? (l0 + 0) : (LTGT - 1)];
    const int i1 = tg[(l0 + 1 < LTGT) ? (l0 + 1) : (LTGT - 1)];
    const int i2 = tg[(l0 + 2 < LTGT) ? (l0 + 2) : (LTGT - 1)];
    const int i3 = tg[(l0 + 3 < LTGT) ? (l0 + 3) : (LTGT - 1)];
    const float* xb = x + b * CVOC;
    __syncthreads();
    float a0 = (lane == 0) ? (xb[i0] - s_lse[0]) : NEG_INF;
    float a1 = NEG_INF, a2 = NEG_INF, a3 = NEG_INF;
    const float* rA = xb + (size_t)1 * BATCH * CVOC;
    float pa0 = rA[i0], pa1 = rA[i1], pa2 = rA[i2], pa3 = rA[i3];
    const float* rB = xb + (size_t)2 * BATCH * CVOC;
    float pb0 = rB[i0], pb1 = rB[i1], pb2 = rB[i2], pb3 = rB[i3];
#define DP_STEP(e0, e1, e2, e3, tt)                                   \
    {                                                                 \
        const float ls = s_lse[tt];                                   \
        float prev = __shfl_up(a3, 1, 64);                            \
        if (lane == 0) prev = NEG_INF;                                \
        const float n0 = ((e0) - ls) + lae(a0, prev);                 \
        const float n1 = ((e1) - ls) + lae(a1, a0);                   \
        const float n2 = ((e2) - ls) + lae(a2, a1);                   \
        const float n3 = ((e3) - ls) + lae(a3, a2);                   \
        a0 = n0; a1 = n1; a2 = n2; a3 = n3;                           \
    }
    int t = 1;
    while (t < T_FRAMES) {
        DP_STEP(pa0, pa1, pa2, pa3, t);
        {
            const int tn = (t + 2 < T_FRAMES) ? (t + 2) : (T_FRAMES - 1);
            const float* r = xb + (size_t)tn * BATCH * CVOC;
            pa0 = r[i0]; pa1 = r[i1]; pa2 = r[i2]; pa3 = r[i3];
        }
        ++t;
        if (t >= T_FRAMES) break;
        DP_STEP(pb0, pb1, pb2, pb3, t);
        {
            const int tn = (t + 2 < T_FRAMES) ? (t + 2) : (T_FRAMES - 1);
            const float* r = xb + (size_t)tn * BATCH * CVOC;
            pb0 = r[i0]; pb1 = r[i1]; pb2 = r[i2]; pb3 = r[i3];
        }
        ++t;
    }
#undef DP_STEP
    const float resv = __shfl(a3, 49, 64);
    if (lane == 0) part[b] = -resv;
}

extern "C" void kernel_launch(void* const* d_in, const int* in_sizes, int n_in,
                              void* d_out, int out_size, void* d_ws, size_t ws_size,
                              hipStream_t stream) {
    const float* x = (const float*)d_in[0];        // [T, B, C] float32
    const int* targets = (const int*)d_in[1];      // [B, L] int32
    float* out = (float*)d_out;

    const size_t emit_bytes = (size_t)BATCH * T_FRAMES * EPAD * sizeof(float); // 102.4 MB
    // fast path needs slack past emit for dp's one-row (800 B) over-read
    if (ws_size >= emit_bytes + 8192) {
        float* emit = (float*)d_ws;
        float* part = (float*)((char*)d_ws + emit_bytes + 4096);
        emit_kernel<<<T_FRAMES * BATCH / 16, 256, 0, stream>>>(x, targets, emit);
        dp_kernel<<<BATCH, 64, 0, stream>>>(emit, part);
        reduce_kernel<<<1, 64, 0, stream>>>(part, out);
    } else {
        float* lse = (float*)d_ws;
        float* part = lse + (size_t)BATCH * T_FRAMES;
        lse_kernel<<<T_FRAMES * BATCH / 4, 256, 0, stream>>>(x, lse);
        dp_slow_kernel<<<BATCH, 64, 0, stream>>>(x, targets, lse, part);
        reduce_kernel<<<1, 64, 0, stream>>>(part, out);
    }
}

// Round 8
// 279.661 us; speedup vs baseline: 3.1729x; 1.3628x over previous
//
#include <hip/hip_runtime.h>

// T=2000 frames, B=64 batch, C=256 vocab, L=200 targets.
#define T_FRAMES 2000
#define BATCH    64
#define CVOC     256
#define LTGT     200
#define EPAD     200                  // emit row stride in floats (800 B, dense)
#define SEG      20                   // dp: rows per register segment (r5-proven)
#define NSEG     100                  // SEG*NSEG covers t=1..2000 (t=2000 discarded)
#define NEG_INF  (-1e30f)
#define INV_LN2  1.4426950408889634f
#define LN2      0.6931471805599453f

// Raw v_exp_f32 (2^x) / v_log_f32 (log2 x). __exp2f/__log2f collide with glibc
// reserved names in the -x hip TU — use the amdgcn builtins.
#if __has_builtin(__builtin_amdgcn_exp2f)
__device__ __forceinline__ float fexp2(float x) { return __builtin_amdgcn_exp2f(x); }
#else
__device__ __forceinline__ float fexp2(float x) { return exp2f(x); }
#endif
#if __has_builtin(__builtin_amdgcn_logf)
__device__ __forceinline__ float flog2(float x) { return __builtin_amdgcn_logf(x); }
#else
__device__ __forceinline__ float flog2(float x) { return log2f(x); }
#endif

// ---------------------------------------------------------------------------
// DPP helpers.
// ---------------------------------------------------------------------------
// wave_shr:1 with 0-fill for lane 0 — 0 is the linear-domain identity.
__device__ __forceinline__ float dpp_shr1_zero(float v) {
    return __int_as_float(__builtin_amdgcn_update_dpp(
        0, __float_as_int(v), 0x138, 0xF, 0xF, true));
}
__device__ __forceinline__ int dpp_shr1_zero_i(int v) {
    return __builtin_amdgcn_update_dpp(0, v, 0x138, 0xF, 0xF, true);
}
template <int CTRL, int RMASK>
__device__ __forceinline__ float dpp_term(float v) {
    return __int_as_float(__builtin_amdgcn_update_dpp(
        0, __float_as_int(v), CTRL, RMASK, 0xF, true));
}
// wave max (exact for non-negative v; 0-fill is the identity), bcast via lane 63.
__device__ __forceinline__ float wave_max(float v) {
    v = fmaxf(v, dpp_term<0x111, 0xF>(v));   // row_shr:1
    v = fmaxf(v, dpp_term<0x112, 0xF>(v));   // row_shr:2
    v = fmaxf(v, dpp_term<0x114, 0xF>(v));   // row_shr:4
    v = fmaxf(v, dpp_term<0x118, 0xF>(v));   // row_shr:8
    v = fmaxf(v, dpp_term<0x142, 0xA>(v));   // row_bcast:15 -> rows 1,3
    v = fmaxf(v, dpp_term<0x143, 0xC>(v));   // row_bcast:31 -> rows 2,3
    return __int_as_float(__builtin_amdgcn_readlane(__float_as_int(v), 63));
}
__device__ __forceinline__ float wave_sum(float v) {
    v += dpp_term<0x111, 0xF>(v);
    v += dpp_term<0x112, 0xF>(v);
    v += dpp_term<0x114, 0xF>(v);
    v += dpp_term<0x118, 0xF>(v);
    v += dpp_term<0x142, 0xA>(v);
    v += dpp_term<0x143, 0xC>(v);
    return __int_as_float(__builtin_amdgcn_readlane(__float_as_int(v), 63));
}

// ---------------------------------------------------------------------------
// Kernel 1: fused log-softmax + target gather, storing LINEAR probabilities:
// emit[b][t][l] = exp(x[t,b,tgt[b,l]] - lse). (Executed fine in r7.)
// ---------------------------------------------------------------------------
__global__ __launch_bounds__(256) void emit_kernel(const float* __restrict__ x,
                                                   const int* __restrict__ targets,
                                                   float* __restrict__ emit) {
    __shared__ float s[16][CVOC];                // 16 KB
    const int w = threadIdx.x >> 6;
    const int lane = threadIdx.x & 63;
    const int r0 = blockIdx.x * 16 + w * 4;      // this wave's 4 rows (r = t*64+b)
    const int li = (lane < 50) ? lane : 49;

    float4 v[4];
#pragma unroll
    for (int k = 0; k < 4; ++k)
        v[k] = ((const float4*)(x + (size_t)(r0 + k) * CVOC))[lane];
    int4 tg[4];
#pragma unroll
    for (int k = 0; k < 4; ++k)
        tg[k] = ((const int4*)(targets + ((r0 + k) & 63) * LTGT))[li];

    float lse2[4];
#pragma unroll
    for (int k = 0; k < 4; ++k) {
        v[k].x *= INV_LN2; v[k].y *= INV_LN2; v[k].z *= INV_LN2; v[k].w *= INV_LN2;
        float m = fmaxf(fmaxf(v[k].x, v[k].y), fmaxf(v[k].z, v[k].w));
        m = wave_max(m);
        float ss = fexp2(v[k].x - m) + fexp2(v[k].y - m) +
                   fexp2(v[k].z - m) + fexp2(v[k].w - m);
        ss = wave_sum(ss);
        lse2[k] = m + flog2(ss);
        ((float4*)&s[w * 4 + k][lane * 4])[0] = v[k];   // same-wave staging
    }

#pragma unroll
    for (int k = 0; k < 4; ++k) {
        if (lane < 50) {
            const int r = r0 + k;
            const int t = r >> 6;
            const int b = r & 63;
            float4 e;
            e.x = fexp2(s[w * 4 + k][tg[k].x] - lse2[k]);   // linear probability
            e.y = fexp2(s[w * 4 + k][tg[k].y] - lse2[k]);
            e.z = fexp2(s[w * 4 + k][tg[k].z] - lse2[k]);
            e.w = fexp2(s[w * 4 + k][tg[k].w] - lse2[k]);
            ((float4*)(emit + ((size_t)b * T_FRAMES + t) * EPAD))[lane] = e;
        }
    }
}

// ---------------------------------------------------------------------------
// Kernel 2: forward DP, LINEAR domain with PER-LANE power-of-2 scale.
// value[l] = z[l] * 2^A(lane). Z'[l] = E[l]*(Z[l]+Z[l-1]); the cross-lane
// term is rescaled with one v_ldexp_f32 per step. Per-lane renorm every 4
// steps; inactive lanes adopt the left neighbor's scale (front propagation).
// Zero transcendentals in the step loop. r5-proven ping-pong skeleton.
// ---------------------------------------------------------------------------
__device__ __forceinline__ float4 ld_row(const float* base, int t, int fi) {
    return ((const float4*)(base + (size_t)t * EPAD))[fi];
}

// Per-lane renorm (exact, power-of-2): bring lane max into [1,2).
// Inactive (all-zero) lanes adopt the left neighbor's (pre-renorm) scale.
__device__ __forceinline__ void renorm(float& z0, float& z1, float& z2, float& z3,
                                       int& A) {
    const float m4 = fmaxf(fmaxf(z0, z1), fmaxf(z2, z3));
    const int Ap = dpp_shr1_zero_i(A);             // left neighbor's A (lane0: 0)
    const bool act = (m4 > 0.0f);
    const int sh = act ? (127 - ((__float_as_int(m4) >> 23) & 255)) : 0;
    z0 = ldexpf(z0, sh); z1 = ldexpf(z1, sh);
    z2 = ldexpf(z2, sh); z3 = ldexpf(z3, sh);
    A = act ? (A - sh) : Ap;
}

__global__ __launch_bounds__(64, 1) void dp_kernel(const float* __restrict__ emit,
                                                   float* __restrict__ part) {
    const int b = blockIdx.x;
    const int lane = threadIdx.x;
    const float* base = emit + (size_t)b * T_FRAMES * EPAD;
    const int fi = (lane < 50) ? lane : 49;

    // init: alpha0[0] = log2(E00): z0 = E00 at lane 0, A = 0; normalize once.
    const float e00 = base[0];
    float z0 = (lane == 0) ? e00 : 0.0f;
    float z1 = 0.0f, z2 = 0.0f, z3 = 0.0f;
    int A = 0;
    renorm(z0, z1, z2, z3, A);

    float res = 1.0f;
    int resA = 0;

    float4 ebA[SEG], ebB[SEG];

#pragma unroll
    for (int j = 0; j < SEG; ++j)                 // segment 0 -> A
        ebA[j] = ld_row(base, 1 + j, fi);

    // One DP step; capture (res,resA) at t == 1999; per-lane renorm every 4.
#define DP_STEP(e, tcur, j)                                           \
    {                                                                 \
        const float p  = dpp_shr1_zero(z3);                           \
        const int   Ap = dpp_shr1_zero_i(A);                          \
        const float pe = ldexpf(p, Ap - A);                           \
        const float n0 = (e).x * (z0 + pe);                           \
        const float n1 = (e).y * (z1 + z0);                           \
        const float n2 = (e).z * (z2 + z1);                           \
        const float n3 = (e).w * (z3 + z2);                           \
        z0 = n0; z1 = n1; z2 = n2; z3 = n3;                           \
        if ((tcur) == T_FRAMES - 1) { res = z3; resA = A; }           \
        if (((j) & 3) == 3) renorm(z0, z1, z2, z3, A);                \
    }

    // NOTE (r5-proven skeleton): segment 99, j=19 touches t=2000 — an 800 B
    // over-read past this batch's rows (covered by ws slack for b=63). Its
    // result is discarded: (res,resA) captured at t==1999 (j=18), before the
    // j=19 step and its renorm.
    for (int sp = 0; sp < NSEG; sp += 2) {
#pragma unroll
        for (int j = 0; j < SEG; ++j)             // segment sp+1 -> B
            ebB[j] = ld_row(base, 1 + (sp + 1) * SEG + j, fi);
#pragma unroll
        for (int j = 0; j < SEG; ++j)             // compute segment sp (A)
            DP_STEP(ebA[j], 1 + sp * SEG + j, j);
        if (sp + 2 < NSEG) {
#pragma unroll
            for (int j = 0; j < SEG; ++j)         // segment sp+2 -> A
                ebA[j] = ld_row(base, 1 + (sp + 2) * SEG + j, fi);
        }
#pragma unroll
        for (int j = 0; j < SEG; ++j)             // compute segment sp+1 (B)
            DP_STEP(ebB[j], 1 + (sp + 1) * SEG + j, j);
    }
#undef DP_STEP

    const float rz = __int_as_float(__builtin_amdgcn_readlane(__float_as_int(res), 49));
    const int rA = __builtin_amdgcn_readlane(resA, 49);
    if (lane == 0) part[b] = -((float)rA + flog2(rz)) * LN2;   // back to nats
}

// ---------------------------------------------------------------------------
// Kernel 3: mean over the 64 per-batch NLLs.
// ---------------------------------------------------------------------------
__global__ __launch_bounds__(64) void reduce_kernel(const float* __restrict__ part,
                                                    float* __restrict__ out) {
    float v = part[threadIdx.x];
#pragma unroll
    for (int s = 1; s < 64; s <<= 1) v += __shfl_xor(v, s, 64);
    if (threadIdx.x == 0) out[0] = v * (1.0f / BATCH);
}

// ===========================================================================
// Fallback path (round-1, natural-log domain, verified) if ws too small.
// ===========================================================================
__device__ __forceinline__ float lae(float a, float b) {
    float m = fmaxf(a, b);
    float d = fminf(a, b) - m;
    return m + __logf(1.0f + __expf(d));
}

__global__ __launch_bounds__(256) void lse_kernel(const float* __restrict__ x,
                                                  float* __restrict__ lse) {
    const int wave = threadIdx.x >> 6;
    const int lane = threadIdx.x & 63;
    const int r = blockIdx.x * 4 + wave;
    float4 v = ((const float4*)(x + (size_t)r * CVOC))[lane];
    float m = fmaxf(fmaxf(v.x, v.y), fmaxf(v.z, v.w));
#pragma unroll
    for (int s = 1; s < 64; s <<= 1) m = fmaxf(m, __shfl_xor(m, s, 64));
    float ssum = __expf(v.x - m) + __expf(v.y - m) + __expf(v.z - m) + __expf(v.w - m);
#pragma unroll
    for (int s = 1; s < 64; s <<= 1) ssum += __shfl_xor(ssum, s, 64);
    if (lane == 0) {
        const int t = r >> 6;
        const int b = r & 63;
        lse[b * T_FRAMES + t] = m + __logf(ssum);
    }
}

__global__ __launch_bounds__(64) void dp_slow_kernel(const float* __restrict__ x,
                                                     const int* __restrict__ targets,
                                                     const float* __restrict__ lse,
                                                     float* __restrict__ part) {
    __shared__ float s_lse[T_FRAMES];
    const int b = blockIdx.x;
    const int lane = threadIdx.x;
    for (int i = lane; i < T_FRAMES; i += 64) s_lse[i] = lse[b * T_FRAMES + i];
    const int* tg = targets + b * LTGT;
    const int l0 = lane * 4;
    const int i0 = tg[(l0 + 0 < LTGT) ? (l0 + 0) : (LTGT - 1)];
    const int i1 = tg[(l0 + 1 < LTGT) ? (l0 + 1) : (LTGT - 1)];
    const int i2 = tg[(l0 + 2 < LTGT) ? (l0 + 2) : (LTGT - 1)];
    const int i3 = tg[(l0 + 3 < LTGT) ? (l0 + 3) : (LTGT - 1)];
    const float* xb = x + b * CVOC;
    __syncthreads();
    float a0 = (lane == 0) ? (xb[i0] - s_lse[0]) : NEG_INF;
    float a1 = NEG_INF, a2 = NEG_INF, a3 = NEG_INF;
    const float* rA = xb + (size_t)1 * BATCH * CVOC;
    float pa0 = rA[i0], pa1 = rA[i1], pa2 = rA[i2], pa3 = rA[i3];
    const float* rB = xb + (size_t)2 * BATCH * CVOC;
    float pb0 = rB[i0], pb1 = rB[i1], pb2 = rB[i2], pb3 = rB[i3];
#define DP_STEP(e0, e1, e2, e3, tt)                                   \
    {                                                                 \
        const float ls = s_lse[tt];                                   \
        float prev = __shfl_up(a3, 1, 64);                            \
        if (lane == 0) prev = NEG_INF;                                \
        const float n0 = ((e0) - ls) + lae(a0, prev);                 \
        const float n1 = ((e1) - ls) + lae(a1, a0);                   \
        const float n2 = ((e2) - ls) + lae(a2, a1);                   \
        const float n3 = ((e3) - ls) + lae(a3, a2);                   \
        a0 = n0; a1 = n1; a2 = n2; a3 = n3;                           \
    }
    int t = 1;
    while (t < T_FRAMES) {
        DP_STEP(pa0, pa1, pa2, pa3, t);
        {
            const int tn = (t + 2 < T_FRAMES) ? (t + 2) : (T_FRAMES - 1);
            const float* r = xb + (size_t)tn * BATCH * CVOC;
            pa0 = r[i0]; pa1 = r[i1]; pa2 = r[i2]; pa3 = r[i3];
        }
        ++t;
        if (t >= T_FRAMES) break;
        DP_STEP(pb0, pb1, pb2, pb3, t);
        {
            const int tn = (t + 2 < T_FRAMES) ? (t + 2) : (T_FRAMES - 1);
            const float* r = xb + (size_t)tn * BATCH * CVOC;
            pb0 = r[i0]; pb1 = r[i1]; pb2 = r[i2]; pb3 = r[i3];
        }
        ++t;
    }
#undef DP_STEP
    const float resv = __shfl(a3, 49, 64);
    if (lane == 0) part[b] = -resv;
}

extern "C" void kernel_launch(void* const* d_in, const int* in_sizes, int n_in,
                              void* d_out, int out_size, void* d_ws, size_t ws_size,
                              hipStream_t stream) {
    const float* x = (const float*)d_in[0];        // [T, B, C] float32
    const int* targets = (const int*)d_in[1];      // [B, L] int32
    float* out = (float*)d_out;

    const size_t emit_bytes = (size_t)BATCH * T_FRAMES * EPAD * sizeof(float); // 102.4 MB
    // fast path needs slack past emit for dp's one-row (800 B) over-read
    if (ws_size >= emit_bytes + 8192) {
        float* emit = (float*)d_ws;
        float* part = (float*)((char*)d_ws + emit_bytes + 4096);
        emit_kernel<<<T_FRAMES * BATCH / 16, 256, 0, stream>>>(x, targets, emit);
        dp_kernel<<<BATCH, 64, 0, stream>>>(emit, part);
        reduce_kernel<<<1, 64, 0, stream>>>(part, out);
    } else {
        float* lse = (float*)d_ws;
        float* part = lse + (size_t)BATCH * T_FRAMES;
        lse_kernel<<<T_FRAMES * BATCH / 4, 256, 0, stream>>>(x, lse);
        dp_slow_kernel<<<BATCH, 64, 0, stream>>>(x, targets, lse, part);
        reduce_kernel<<<1, 64, 0, stream>>>(part, out);
    }
}